// Round 14
// baseline (253.617 us; speedup 1.0000x reference)
//
#include <hip/hip_runtime.h>

// SkeletonConv via MFMA: out[b,o,h,w] = sum_{c,k} W[o,c,k]*x[b,c,h,w+k-1] (dil=1,step=0)
// B=64, C_in=C_out=16, K=3, H=W=256, fp32 in/out; bf16 MFMA compute (threshold 0.1725
// was set for bf16). GEMM form: D[o, w16] = A1(16x32)*B1 + A2(16x32)*B2 per 16-w tile:
//   MFMA#1 K-rows: [tap-1 c0-15 | tap0 c0-15];  MFMA#2: [tap+1 c0-15 | zeros].
// Fragments from global dword loads (64B-segment coalesced, taps L1-hit), packed with
// v_cvt_pk_bf16_f32. No LDS, no shfl. ~230 instr/thread -> FMA floor (41us) leaves the
// VALU pipe; kernel is memory-bound (~60us floor).
// Layout facts (learn_hip): A/B: row/col = lane&15, k = 8*(lane>>4)+j contiguous (m92);
// C/D: col = lane&15, row = (lane>>4)*4 + reg (m89, dtype-independent).
// Ledger: R1 157 / R2 2660 / R3 272 / R4 477 / R5 387 / R6 148 / R7 114.7 best-VALU /
// R8 127.9 / R9 167 / R10 237 / R11 299 / R12 120.9 / R13 272 (o-split latency-starved).

constexpr int CIN = 16, COUT = 16, KK = 3, H = 256, W = 256;

typedef short bf16x8 __attribute__((ext_vector_type(8)));   // 4 VGPRs, 8 bf16
typedef float f32x4  __attribute__((ext_vector_type(4)));
typedef int   i32x4  __attribute__((ext_vector_type(4)));

__device__ __forceinline__ int cvtpk(float lo, float hi) {
    int r;
    asm("v_cvt_pk_bf16_f32 %0, %1, %2" : "=v"(r) : "v"(lo), "v"(hi));
    return r;   // low16 = bf16(lo), high16 = bf16(hi)
}
__device__ __forceinline__ bf16x8 pack8(const float* v) {
    i32x4 r{cvtpk(v[0], v[1]), cvtpk(v[2], v[3]), cvtpk(v[4], v[5]), cvtpk(v[6], v[7])};
    return __builtin_bit_cast(bf16x8, r);
}

__global__ __launch_bounds__(256)
void skel_conv_kernel(const float* __restrict__ x, const float* __restrict__ wgt,
                      const int* __restrict__ dil_p, const int* __restrict__ step_p,
                      float* __restrict__ out, int B)
{
    const int dil  = dil_p[0];
    const int step = step_p[0];

    const int h = blockIdx.x & (H - 1);    // block = one (b,h) row
    const int b = blockIdx.x >> 8;
    if (b >= B) return;
    const size_t cs = (size_t)H * W;

    if (dil == 1 && step == 0) {
        const int lane = threadIdx.x & 63, wv = threadIdx.x >> 6;
        const int g = lane >> 4;           // 16-lane group 0..3
        const int n = lane & 15;           // A-row (=o) / B-col (=w) index
        const int cb = (g & 1) * 8;        // c-chunk base for this group's 8 K-elems

        // ---- A fragments (weights), once per thread ----
        // MFMA#1 K-rows: r<16 -> tap0(off=-1) c=r ; r>=16 -> tap1(off=0) c=r-16
        // lane j-th elem: k=8g+j -> tap=(g>>1), c=cb+j
        float av[8];
        const int tapA1 = g >> 1;
        #pragma unroll
        for (int j = 0; j < 8; ++j)
            av[j] = wgt[(n * CIN + cb + j) * KK + tapA1];
        const bf16x8 a1 = pack8(av);
        // MFMA#2 K-rows: r<16 -> tap2(off=+1) c=r ; r>=16 -> zeros
        #pragma unroll
        for (int j = 0; j < 8; ++j)
            av[j] = (g < 2) ? wgt[(n * CIN + cb + j) * KK + 2] : 0.f;
        const bf16x8 a2 = pack8(av);

        const float* xb = x   + (size_t)b * CIN  * cs + (size_t)h * W;
        float*       ob = out + (size_t)b * COUT * cs + (size_t)h * W;
        const int off1 = (g >> 1) - 1;     // B1 col offset: g01 -> -1 (tap0), g23 -> 0 (tap1)

        #pragma unroll 1
        for (int t = 0; t < 4; ++t) {      // 4 tiles of 16 w per wave
            const int n0 = wv * 64 + t * 16;
            float bv[8];

            const int  w1  = n0 + n + off1;
            const bool ok1 = (w1 >= 0);                    // left zero-pad (w1<=255 always)
            #pragma unroll
            for (int j = 0; j < 8; ++j)
                bv[j] = ok1 ? xb[(size_t)(cb + j) * cs + w1] : 0.f;
            const bf16x8 b1 = pack8(bv);

            const int  w2  = n0 + n + 1;                   // B2: tap+1 for g01, zeros g23
            const bool ok2 = (g < 2) && (w2 < W);          // right zero-pad
            #pragma unroll
            for (int j = 0; j < 8; ++j)
                bv[j] = ok2 ? xb[(size_t)(cb + j) * cs + w2] : 0.f;
            const bf16x8 b2 = pack8(bv);

            f32x4 d{0.f, 0.f, 0.f, 0.f};
            d = __builtin_amdgcn_mfma_f32_16x16x32_bf16(a1, b1, d, 0, 0, 0);
            d = __builtin_amdgcn_mfma_f32_16x16x32_bf16(a2, b2, d, 0, 0, 0);

            // D: col = n (w = n0+n), row = 4g + r (o)
            #pragma unroll
            for (int r = 0; r < 4; ++r)
                ob[(size_t)(4 * g + r) * cs + (n0 + n)] = d[r];
        }
    } else {
        // Generic path: one thread = one pixel, clamped loads + select (any dil/step).
        const int w = threadIdx.x;
        float acc[COUT];
        #pragma unroll
        for (int o = 0; o < COUT; ++o) acc[o] = 0.f;
        #pragma unroll 1
        for (int c = 0; c < CIN; ++c) {
            const float* xc = x + (size_t)b * CIN * cs + (size_t)c * cs;
            #pragma unroll
            for (int k = 0; k < KK; ++k) {
                const int off = k - KK / 2;
                const int hh  = h + off * step;
                const int ww  = w + off * dil;
                const bool ok = (hh >= 0) && (hh < H) && (ww >= 0) && (ww < W);
                const int hcl = hh < 0 ? 0 : (hh > H - 1 ? H - 1 : hh);
                const int wcl = ww < 0 ? 0 : (ww > W - 1 ? W - 1 : ww);
                float v = xc[(size_t)hcl * W + wcl];
                v = ok ? v : 0.f;
                #pragma unroll
                for (int o = 0; o < COUT; ++o)
                    acc[o] = fmaf(wgt[((size_t)o * CIN + c) * KK + k], v, acc[o]);
            }
        }
        float* op = out + (size_t)b * COUT * cs + (size_t)h * W + w;
        #pragma unroll
        for (int o = 0; o < COUT; ++o)
            op[(size_t)o * cs] = acc[o];
    }
}

extern "C" void kernel_launch(void* const* d_in, const int* in_sizes, int n_in,
                              void* d_out, int out_size, void* d_ws, size_t ws_size,
                              hipStream_t stream) {
    const float* x    = (const float*)d_in[0];
    const float* wgt  = (const float*)d_in[1];
    const int*   dil  = (const int*)d_in[2];
    const int*   step = (const int*)d_in[3];
    float*       out  = (float*)d_out;

    const int B = in_sizes[0] / (CIN * H * W);
    const int grid = B * H;                    // one block (4 waves) per (b,h) row
    skel_conv_kernel<<<grid, 256, 0, stream>>>(x, wgt, dil, step, out, B);
}

// Round 15
// 136.955 us; speedup vs baseline: 1.8518x; 1.8518x over previous
//
#include <hip/hip_runtime.h>

// SkeletonConv via MFMA + LDS staging. out[b,o,h,w] = sum_{c,k} W[o,c,k]*x[b,c,h,w+k-1].
// B=64, C_in=C_out=16, K=3, H=W=256, fp32 in/out, bf16 MFMA compute (verified R14:
// absmax 0.0625 << 0.1725 threshold).
// R15: R14's verified GEMM mapping, but B-fragments fed from an LDS-staged row:
//   stage [16c][256w] via 16x global_load_lds w=16 (R5-proven: FETCH/WRITE exact,
//   no spill), row pad 257 -> bank (c+w)%32, ds_read_b32 pairs packed IMMEDIATELY
//   into named ints via v_cvt_pk_bf16_f32 (R14's float arrays spilled at VGPR=28).
// MFMA per 16-w tile: #1 K-rows [tap0 c0-15 | tap1 c0-15], #2 [tap2 c0-15 | 0].
// A/B layout: row/col = lane&15, k = 8*(lane>>4)+j (m92); C/D: col=lane&15,
// row=4*(lane>>4)+reg (m89). Ledger: R7 114.7 best-VALU / R14 300 (MFMA, spill +
// uncoalesced B loads, but numerics verified).

constexpr int CIN = 16, COUT = 16, KK = 3, H = 256, W = 256;
constexpr int LROW = W + 1;            // 257: LDS row pad -> bank = (c+w)%32

typedef short bf16x8 __attribute__((ext_vector_type(8)));   // 4 VGPRs, 8 bf16
typedef float f32x4  __attribute__((ext_vector_type(4)));
typedef int   i32x4  __attribute__((ext_vector_type(4)));

__device__ __forceinline__ int cvtpk(float lo, float hi) {
    int r;
    asm("v_cvt_pk_bf16_f32 %0, %1, %2" : "=v"(r) : "v"(lo), "v"(hi));
    return r;   // low16 = bf16(lo), high16 = bf16(hi)
}

__global__ __launch_bounds__(256)
void skel_conv_kernel(const float* __restrict__ x, const float* __restrict__ wgt,
                      const int* __restrict__ dil_p, const int* __restrict__ step_p,
                      float* __restrict__ out, int B)
{
    const int dil  = dil_p[0];
    const int step = step_p[0];

    const int h = blockIdx.x & (H - 1);    // block = one (b,h) row (uniform)
    const int b = blockIdx.x >> 8;
    if (b >= B) return;
    const size_t cs = (size_t)H * W;

    __shared__ float xs[CIN * LROW];       // 16.4 KB staged row

    if (dil == 1 && step == 0) {
        const int t = threadIdx.x, lane = t & 63, wv = t >> 6;

        // ---- stage: 16 x 1KB DMA (wave wv -> channels 4wv..4wv+3), linear dest ----
        const float* src = x + (size_t)b * CIN * cs + (size_t)h * W + lane * 4;
        #pragma unroll
        for (int i = 0; i < 4; ++i) {
            const int c = wv * 4 + i;
            __builtin_amdgcn_global_load_lds(
                (const __attribute__((address_space(1))) void*)(src + (size_t)c * cs),
                (__attribute__((address_space(3))) void*)&xs[c * LROW], 16, 0, 0);
        }
        __syncthreads();                   // vmcnt(0) + barrier

        // ---- A fragments (weights), once; named ints only ----
        const int g = lane >> 4;           // 16-lane group
        const int n = lane & 15;           // A-row (=o) / B-col (=w)
        const int cb = (g & 1) * 8;        // c-chunk for this group's 8 K-elems
        const int tap1 = g >> 1;           // MFMA#1: g01 -> tap k=0, g23 -> tap k=1
        const float* wb = wgt + (n * CIN + cb) * KK;
        const int a10 = cvtpk(wb[0 * KK + tap1], wb[1 * KK + tap1]);
        const int a11 = cvtpk(wb[2 * KK + tap1], wb[3 * KK + tap1]);
        const int a12 = cvtpk(wb[4 * KK + tap1], wb[5 * KK + tap1]);
        const int a13 = cvtpk(wb[6 * KK + tap1], wb[7 * KK + tap1]);
        const bf16x8 a1 = __builtin_bit_cast(bf16x8, i32x4{a10, a11, a12, a13});
        const bool glo = (g < 2);          // MFMA#2: K-rows 16-31 are zero
        const int a20 = glo ? cvtpk(wb[0 * KK + 2], wb[1 * KK + 2]) : 0;
        const int a21 = glo ? cvtpk(wb[2 * KK + 2], wb[3 * KK + 2]) : 0;
        const int a22 = glo ? cvtpk(wb[4 * KK + 2], wb[5 * KK + 2]) : 0;
        const int a23 = glo ? cvtpk(wb[6 * KK + 2], wb[7 * KK + 2]) : 0;
        const bf16x8 a2 = __builtin_bit_cast(bf16x8, i32x4{a20, a21, a22, a23});

        float* ob = out + (size_t)b * COUT * cs + (size_t)h * W;
        const int off1 = tap1 - 1;         // B1 col offset: tap0 -> -1, tap1 -> 0

        #pragma unroll
        for (int tt = 0; tt < 4; ++tt) {   // 4 tiles of 16 w per wave
            const int n0 = wv * 64 + tt * 16;

            // B1: x[cb+j][n0+n+off1], zero at left pad (w1 < 0)
            const int  w1  = n0 + n + off1;
            const bool ok1 = (w1 >= 0);
            const float* L1 = &xs[cb * LROW + (ok1 ? w1 : 0)];
            const float u0 = L1[0 * LROW], u1 = L1[1 * LROW];
            const float u2 = L1[2 * LROW], u3 = L1[3 * LROW];
            const float u4 = L1[4 * LROW], u5 = L1[5 * LROW];
            const float u6 = L1[6 * LROW], u7 = L1[7 * LROW];
            const int b10 = ok1 ? cvtpk(u0, u1) : 0;
            const int b11 = ok1 ? cvtpk(u2, u3) : 0;
            const int b12 = ok1 ? cvtpk(u4, u5) : 0;
            const int b13 = ok1 ? cvtpk(u6, u7) : 0;
            const bf16x8 B1 = __builtin_bit_cast(bf16x8, i32x4{b10, b11, b12, b13});

            // B2: tap+1 for g01 (zero at right pad w2==W); anything for g23 (A2=0)
            const int  w2  = n0 + n + 1;
            const bool ok2 = glo && (w2 < W);
            const float* L2 = &xs[cb * LROW + (w2 < W ? w2 : 0)];
            const float s0 = L2[0 * LROW], s1 = L2[1 * LROW];
            const float s2 = L2[2 * LROW], s3 = L2[3 * LROW];
            const float s4 = L2[4 * LROW], s5 = L2[5 * LROW];
            const float s6 = L2[6 * LROW], s7 = L2[7 * LROW];
            const int b20 = ok2 ? cvtpk(s0, s1) : 0;
            const int b21 = ok2 ? cvtpk(s2, s3) : 0;
            const int b22 = ok2 ? cvtpk(s4, s5) : 0;
            const int b23 = ok2 ? cvtpk(s6, s7) : 0;
            const bf16x8 B2 = __builtin_bit_cast(bf16x8, i32x4{b20, b21, b22, b23});

            f32x4 d{0.f, 0.f, 0.f, 0.f};
            d = __builtin_amdgcn_mfma_f32_16x16x32_bf16(a1, B1, d, 0, 0, 0);
            d = __builtin_amdgcn_mfma_f32_16x16x32_bf16(a2, B2, d, 0, 0, 0);

            // D: col = n (w = n0+n), row = 4g + r (o)
            float* op = ob + (size_t)(4 * g) * cs + (n0 + n);
            op[0 * cs] = d[0];
            op[1 * cs] = d[1];
            op[2 * cs] = d[2];
            op[3 * cs] = d[3];
        }
    } else {
        // Generic path: one thread = one pixel, clamped loads + select (any dil/step).
        const int w = threadIdx.x;
        float acc[COUT];
        #pragma unroll
        for (int o = 0; o < COUT; ++o) acc[o] = 0.f;
        #pragma unroll 1
        for (int c = 0; c < CIN; ++c) {
            const float* xc = x + (size_t)b * CIN * cs + (size_t)c * cs;
            #pragma unroll
            for (int k = 0; k < KK; ++k) {
                const int off = k - KK / 2;
                const int hh  = h + off * step;
                const int ww  = w + off * dil;
                const bool ok = (hh >= 0) && (hh < H) && (ww >= 0) && (ww < W);
                const int hcl = hh < 0 ? 0 : (hh > H - 1 ? H - 1 : hh);
                const int wcl = ww < 0 ? 0 : (ww > W - 1 ? W - 1 : ww);
                float v = xc[(size_t)hcl * W + wcl];
                v = ok ? v : 0.f;
                #pragma unroll
                for (int o = 0; o < COUT; ++o)
                    acc[o] = fmaf(wgt[((size_t)o * CIN + c) * KK + k], v, acc[o]);
            }
        }
        float* op = out + (size_t)b * COUT * cs + (size_t)h * W + w;
        #pragma unroll
        for (int o = 0; o < COUT; ++o)
            op[(size_t)o * cs] = acc[o];
    }
}

extern "C" void kernel_launch(void* const* d_in, const int* in_sizes, int n_in,
                              void* d_out, int out_size, void* d_ws, size_t ws_size,
                              hipStream_t stream) {
    const float* x    = (const float*)d_in[0];
    const float* wgt  = (const float*)d_in[1];
    const int*   dil  = (const int*)d_in[2];
    const int*   step = (const int*)d_in[3];
    float*       out  = (float*)d_out;

    const int B = in_sizes[0] / (CIN * H * W);
    const int grid = B * H;                    // one block (4 waves) per (b,h) row
    skel_conv_kernel<<<grid, 256, 0, stream>>>(x, wgt, dil, step, out, B);
}